// Round 8
// baseline (141.762 us; speedup 1.0000x reference)
//
#include <hip/hip_runtime.h>
#include <stdint.h>

// Problem constants
#define NB 4
#define NS 2048
#define NH 16
#define ND 64
#define NHD 1024   // H*D
#define NK 1024    // DQ = DK

typedef __attribute__((ext_vector_type(8))) short short8;
typedef __attribute__((ext_vector_type(4))) float f32x4;
typedef __attribute__((ext_vector_type(16))) float f32x16;
typedef __attribute__((ext_vector_type(4))) unsigned u32x4;

__device__ __forceinline__ unsigned short f2bf(float f) {
    union { float f; unsigned u; } v; v.f = f;
    return (unsigned short)((v.u + 0x7fffu + ((v.u >> 16) & 1u)) >> 16);  // RNE
}

__device__ __forceinline__ void gload_lds16(const unsigned short* g, unsigned short* l) {
    __builtin_amdgcn_global_load_lds(
        (const __attribute__((address_space(1))) void*)g,
        (__attribute__((address_space(3))) void*)l, 16, 0, 0);
}

__device__ __forceinline__ unsigned cvtpk(float lo, float hi) {
    unsigned r;
    asm volatile("v_cvt_pk_bf16_f32 %0, %1, %2" : "=v"(r) : "v"(lo), "v"(hi));
    return r;
}
__device__ __forceinline__ void plswap(unsigned& a, unsigned& b) {
    asm volatile("v_permlane32_swap_b32 %0, %1" : "+v"(a), "+v"(b));
}
// raw v_exp_f32: exact for our bounded inputs (|x| <= ~30), avoids libm fixup code
__device__ __forceinline__ float exp2_raw(float x) {
    float r;
    asm("v_exp_f32 %0, %1" : "=v"(r) : "v"(x));
    return r;
}

// ---------------- merged W cvt: both weight matrices in one launch ----------------
__global__ void cvt_w_bf16(const float* __restrict__ Wq, const float* __restrict__ Wk,
                           unsigned short* __restrict__ Wqb, unsigned short* __restrict__ Wkb) {
    const int n4 = (NK * NHD) / 4;   // per matrix
    const int stride = gridDim.x * blockDim.x;
    for (int i = blockIdx.x * blockDim.x + threadIdx.x; i < 2 * n4; i += stride) {
        const int m = i < n4 ? 0 : 1;
        const int j = m ? i - n4 : i;
        const float4 v = m ? ((const float4*)Wk)[j] : ((const float4*)Wq)[j];
        ushort4 o;
        o.x = f2bf(v.x); o.y = f2bf(v.y); o.z = f2bf(v.z); o.w = f2bf(v.w);
        if (m) ((ushort4*)Wkb)[j] = o; else ((ushort4*)Wqb)[j] = o;
    }
}

// ---------------- projection GEMM: 128x512 tile, BK=64, 8 waves, 4-phase interleave -------
// R8: halve the A-path redundancy.  R5/R6 isolated the in-loop fp32 A path (flat loads +
// cvtpk + ds_write) as proj's marginal cost (~10us GPU-wide at x4 redundancy).  Retile
// 256x256 -> 128x512: n-blocks per A-panel 4 -> 2, so total A-path work halves; B staging
// doubles per block but is pure global_load_lds DMA (W stays L2-served, same m-redundancy).
// Same grid (256 = 1 block/CU), same 64 MFMA/K-step/wave, same acc footprint (32 f32x4).
// LDS = A 2x16K + B 2x64K = 160 KiB (full pool, opt-in).  K order unchanged -> bit-identical.
#define PH_SYNC() do { __builtin_amdgcn_s_barrier(); __builtin_amdgcn_sched_barrier(0); \
    asm volatile("s_waitcnt lgkmcnt(0)" ::: "memory"); __builtin_amdgcn_sched_barrier(0); } while (0)
#define PH_END()  do { __builtin_amdgcn_s_barrier(); __builtin_amdgcn_sched_barrier(0); } while (0)

#define RD_AF(KK)                                                                         \
    _Pragma("unroll")                                                                     \
    for (int mi_ = 0; mi_ < 4; ++mi_) {                                                   \
        const int rowA_ = wm + mi_ * 16 + lr;                                             \
        af[mi_] = *(const short8*)(Ab + (rowA_ << 7) + (((KK) * 64 + lg * 16) ^ swzr));   \
    }
#define RD_BF(KK, NHF)                                                                    \
    _Pragma("unroll")                                                                     \
    for (int ni_ = 0; ni_ < 4; ++ni_) {                                                   \
        const int rowB_ = wn + (NHF) * 64 + ni_ * 16 + lr;                                \
        bfr[ni_] = *(const short8*)(Bb + (rowB_ << 7) + (((KK) * 64 + lg * 16) ^ swzr));  \
    }
#define DO_MFMA(NHF)                                                                      \
    do {                                                                                  \
        __builtin_amdgcn_s_setprio(1);                                                    \
        _Pragma("unroll")                                                                 \
        for (int mi_ = 0; mi_ < 4; ++mi_)                                                 \
            _Pragma("unroll")                                                             \
            for (int ni_ = 0; ni_ < 4; ++ni_)                                             \
                acc[mi_][(NHF) * 4 + ni_] = __builtin_amdgcn_mfma_f32_16x16x32_bf16(      \
                    af[mi_], bfr[ni_], acc[mi_][(NHF) * 4 + ni_], 0, 0, 0);               \
        __builtin_amdgcn_s_setprio(0);                                                    \
    } while (0)

__global__ __launch_bounds__(512, 2) void proj_gemm5(
    const float* __restrict__ Xq,
    const float* __restrict__ Xk,
    const unsigned short* __restrict__ Wqb,
    const unsigned short* __restrict__ Wkb,
    const float* __restrict__ bqv,
    const float* __restrict__ bkv,
    unsigned short* __restrict__ Qo,
    unsigned short* __restrict__ Ko,
    unsigned short* __restrict__ KTo,
    float qscale)
{
    // dynamic LDS, 160 KiB: A0 @0 (16K), A1 @16K, B0 @32K (64K), B1 @96K
    extern __shared__ __attribute__((aligned(16))) char smem[];

    // XCD-aware bijective remap: XCD x owns 16 consecutive m-panels x both n-halves ->
    // A panels L2-shared by their 2 blocks; W n-halves (1MB) resident per XCD.
    const int bid = blockIdx.x;
    const int wg = (bid & 7) * 32 + (bid >> 3);
    const int mp = wg >> 1;            // 0..127  (0..63 = Q rows, 64..127 = K rows)
    const int nb = wg & 1;             // 0..1
    const int which = mp >> 6;
    const long bm = (long)(mp & 63) * 128;
    const long bn = (long)nb * 512;

    const float* A32         = which ? Xk : Xq;
    const unsigned short* Wt = which ? Wkb : Wqb;
    const float* bias        = which ? bkv : bqv;
    unsigned short* outp     = which ? Ko : Qo;
    unsigned short* outT     = which ? KTo : nullptr;
    const float scale        = which ? 1.0f : qscale;

    const int t = threadIdx.x;
    const int lane = t & 63;
    const int w = t >> 6;                       // 0..7
    const int wm = (w >> 2) * 64, wn = (w & 3) * 128;   // wave tile 64m x 128n
    const int lr = lane & 15, lg = lane >> 4;
    const int swzr = (lr & 7) << 4;

    f32x4 acc[4][8];
    #pragma unroll
    for (int i = 0; i < 4; ++i)
        #pragma unroll
        for (int jj = 0; jj < 8; ++jj) acc[i][jj] = (f32x4){0.f, 0.f, 0.f, 0.f};

    float4 aset[4];   // single in-flight fp32 A set (16 floats/thread)

    auto LOADA = [&](int k0) {
        #pragma unroll
        for (int c = 0; c < 2; ++c) {
            const int u2 = c * 512 + t;
            const int row = u2 >> 3, c8 = u2 & 7;   // 128 rows x 8 chunks
            const float* src = A32 + (bm + row) * (long)NK + k0 + c8 * 8;
            aset[2 * c]     = *(const float4*)src;
            aset[2 * c + 1] = *(const float4*)(src + 4);
        }
    };
    auto WRITEA = [&](int buf) {
        char* Ad = smem + buf * 16384;
        #pragma unroll
        for (int c = 0; c < 2; ++c) {
            const int u2 = c * 512 + t;
            const int row = u2 >> 3;
            const int cbyte = ((u2 & 7) << 4) ^ ((row & 7) << 4);   // T2 swizzle
            u32x4 wv;
            wv[0] = cvtpk(aset[2 * c].x, aset[2 * c].y);
            wv[1] = cvtpk(aset[2 * c].z, aset[2 * c].w);
            wv[2] = cvtpk(aset[2 * c + 1].x, aset[2 * c + 1].y);
            wv[3] = cvtpk(aset[2 * c + 1].z, aset[2 * c + 1].w);
            *(u32x4*)(Ad + (row << 7) + cbyte) = wv;
        }
    };
    const int scolB = (((lane & 7) ^ (lane >> 3)) << 3);   // pre-swizzled global source
    // B-tile 512 rows x 64 K = 64 KB, staged in two halves of 4 gloads/thread each
    auto BGLOAD = [&](int k0, int buf, int half) {
        unsigned short* Bd = (unsigned short*)(smem + 32768 + buf * 65536);
        #pragma unroll
        for (int c = 0; c < 4; ++c) {
            const int rowB = half * 256 + c * 64 + w * 8 + (lane >> 3);
            gload_lds16(Wt + (bn + rowB) * (long)NK + k0 + scolB,
                        Bd + (size_t)rowB * 64);
        }
    };

    // ---- prologue: B(0) both halves, A(0) staged; A(1) in flight ----
    BGLOAD(0, 0, 0); BGLOAD(0, 0, 1);                // 8 vm
    asm volatile("" ::: "memory");
    LOADA(0);                                        // 4 vm
    asm volatile("" ::: "memory");
    WRITEA(0);                                       // compiler vmcnt drains B(0)+A(0)
    __builtin_amdgcn_sched_barrier(0);
    LOADA(64);                                       // A(1), 4 vm, stays in flight
    asm volatile("s_waitcnt lgkmcnt(0)" ::: "memory");
    __builtin_amdgcn_s_barrier();
    __builtin_amdgcn_sched_barrier(0);

    for (int it = 0; it < 16; ++it) {
        const int cur = it & 1;
        const char* Ab = (const char*)smem + cur * 16384;
        const char* Bb = (const char*)smem + 32768 + cur * 65536;
        short8 af[4], bfr[4];

        // ---- phase 0: kk=0, n-half 0; issue B(it+1) half 0 ----
        RD_BF(0, 0); RD_AF(0);
        if (it + 1 < 16) BGLOAD((it + 1) * 64, cur ^ 1, 0);
        PH_SYNC(); DO_MFMA(0); PH_END();

        // ---- phase 1: kk=0, n-half 1; convert+write A(it+1) ----
        RD_BF(0, 1);
        if (it + 1 < 16) WRITEA(cur ^ 1);            // implicit wait retires A(it+1) only
        PH_SYNC(); DO_MFMA(1); PH_END();

        // ---- phase 2: kk=1, n-half 0; issue B(it+1) half 1 + A(it+2) ----
        RD_BF(1, 0); RD_AF(1);
        if (it + 1 < 16) BGLOAD((it + 1) * 64, cur ^ 1, 1);
        if (it + 2 < 16) LOADA((it + 2) * 64);
        PH_SYNC(); DO_MFMA(0); PH_END();

        // ---- phase 3: kk=1, n-half 1; retire B(it+1), keep A(it+2) flying ----
        RD_BF(1, 1);
        if (it + 2 < 16)      asm volatile("s_waitcnt vmcnt(4)" ::: "memory");
        else if (it + 1 < 16) asm volatile("s_waitcnt vmcnt(0)" ::: "memory");
        PH_SYNC(); DO_MFMA(1); PH_END();
    }

    // ---- epilogue: bias + scale + bf16 store, row-burst order (R7) ----
    // Wave's 128-col n-slice spans TWO heads: nh half selects head h0+nh.
    const int h0 = (int)((bn + wn) >> 6);
    float bvv[8];
    #pragma unroll
    for (int nj = 0; nj < 8; ++nj) bvv[nj] = bias[(int)bn + wn + nj * 16 + lr];
    #pragma unroll
    for (int mi = 0; mi < 4; ++mi) {
        const int m0 = (int)bm + wm + mi * 16 + lg * 4;
        const int b = m0 >> 11, s0 = m0 & 2047;
        unsigned short vv[8][4];
        #pragma unroll
        for (int nj = 0; nj < 8; ++nj)
            #pragma unroll
            for (int r = 0; r < 4; ++r)
                vv[nj][r] = f2bf((acc[mi][nj][r] + bvv[nj]) * scale);
        #pragma unroll
        for (int r = 0; r < 4; ++r)
            #pragma unroll
            for (int nh = 0; nh < 2; ++nh) {
                unsigned short* orow = outp +
                    (((size_t)(b * NH + h0 + nh)) * NS + (s0 + r)) * ND;
                #pragma unroll
                for (int ni = 0; ni < 4; ++ni)
                    orow[ni * 16 + lr] = vv[nh * 4 + ni][r];
            }
        if (outT) {
            #pragma unroll
            for (int nh = 0; nh < 2; ++nh)
                #pragma unroll
                for (int ni = 0; ni < 4; ++ni) {
                    const int d = ni * 16 + lr;
                    const int nj = nh * 4 + ni;
                    ushort4 tv; tv.x = vv[nj][0]; tv.y = vv[nj][1];
                    tv.z = vv[nj][2]; tv.w = vv[nj][3];
                    *(ushort4*)&outT[(((size_t)(b * NH + h0 + nh)) * ND + d) * NS + s0] = tv;
                }
        }
    }
}

// max-free P pack + f32 row-half-sum: paw = bf16 A-frags of exp2(S); lsum += sum(P)
// Numerics: |S_log2| <= ~12 (input-licensed), exp2(S) in [2^-12, 2^12] — no max needed.
#define PACK_P(s0, s1, paw, lsum)                                              \
    do {                                                                       \
        _Pragma("unroll")                                                      \
        for (int tt_ = 0; tt_ < 2; ++tt_) {                                    \
            unsigned c_[8];                                                    \
            _Pragma("unroll")                                                  \
            for (int j_ = 0; j_ < 8; ++j_) {                                   \
                const float plo_ = exp2_raw(tt_ ? s1[2 * j_]     : s0[2 * j_]);   \
                const float phi_ = exp2_raw(tt_ ? s1[2 * j_ + 1] : s0[2 * j_ + 1]); \
                (lsum) += plo_ + phi_;                                         \
                c_[j_] = cvtpk(plo_, phi_);                                    \
            }                                                                  \
            plswap(c_[0], c_[2]); plswap(c_[1], c_[3]);                        \
            plswap(c_[4], c_[6]); plswap(c_[5], c_[7]);                        \
            paw[2 * tt_]     = (u32x4){c_[0], c_[1], c_[2], c_[3]};            \
            paw[2 * tt_ + 1] = (u32x4){c_[4], c_[5], c_[6], c_[7]};            \
        }                                                                      \
    } while (0)

// ---------------- fused flash attention: 8-wave blocks, KVBLK=128 (2 sub-tiles/sync) ----
// Proven 82.0us version — frozen (structural plateau: MfmaUtil 37 + VALUBusy 46 ~= pipe
// sum saturated; isolated grafts measured null/negative in R2-R4).
__global__ __launch_bounds__(512, 4) void attn_fused(
    const unsigned short* __restrict__ Qb,
    const unsigned short* __restrict__ Kb,
    const unsigned short* __restrict__ KTb,
    float* __restrict__ outp)
{
    // 2 buffers x { Ka[64][64] @0, KTa @8K, Kb[64][64] @16K, KTb @24K }, rows XOR-swizzled
    __shared__ __attribute__((aligned(16))) unsigned short LDSA[2 * 4 * 4096];  // 64 KiB

    const int t = threadIdx.x;
    const int lane = t & 63;
    const int wq = t >> 6;          // 0..7
    const int q5 = lane & 31;
    const int hi = lane >> 5;

    // XCD-aware remap: all 8 q-blocks of one (b,h) share an XCD => K/KT L2-resident.
    const int Bid = blockIdx.x + 8 * blockIdx.y + 128 * blockIdx.z;   // 0..511 linear
    const int xcd = Bid & 7;
    const int wIdx = Bid >> 3;      // 0..63
    const int qblk = wIdx & 7;      // 8 q-blocks x 256 q
    const int g = xcd * 8 + (wIdx >> 3);
    const int h = g & 15, b = g >> 4;
    const int qbase = qblk * 256 + wq * 32;

    const unsigned short* Qh  = Qb  + ((size_t)(b * NH + h)) * NS * ND;
    const unsigned short* Kh  = Kb  + ((size_t)(b * NH + h)) * NS * ND;
    const unsigned short* KTh = KTb + ((size_t)(b * NH + h)) * ND * NS;

    // Q fragments (B-operand): col = q5, k(d) = kd*16 + hi*8 + e
    short8 qB[4];
    {
        const unsigned short* Qrow = Qh + (size_t)(qbase + q5) * ND;
        #pragma unroll
        for (int kd = 0; kd < 4; ++kd)
            qB[kd] = *(const short8*)&Qrow[kd * 16 + hi * 8];
    }

    // staging: one 1KB chunk per thread per array (8 waves cover 8 chunks)
    const int srow = wq * 8 + (lane >> 3);
    const int scol = ((((lane & 7) << 4) ^ ((srow & 7) << 4)) >> 1);

    f32x16 acc0, acc1;
    float l_run = 0.f;
    #pragma unroll
    for (int r = 0; r < 16; ++r) { acc0[r] = 0.f; acc1[r] = 0.f; }

    const int swz = (q5 & 7) << 4;
    const int ro0 = q5 * 128, ro1 = ro0 + 4096;

    auto STAGE = [&](int buf, int kt /*kv base, mult of 128*/) {
        unsigned short* Bd = &LDSA[buf * 16384];
        gload_lds16(Kh  + (size_t)(kt + srow) * ND + scol,        Bd         + wq * 512);
        gload_lds16(KTh + (size_t)srow * NS + kt + scol,          Bd + 4096  + wq * 512);
        gload_lds16(Kh  + (size_t)(kt + 64 + srow) * ND + scol,   Bd + 8192  + wq * 512);
        gload_lds16(KTh + (size_t)srow * NS + (kt + 64) + scol,   Bd + 12288 + wq * 512);
    };

    // one 64-kv sub-tile: QK^T (swapped) -> PACK -> PV, all registers local
    auto COMPUTE = [&](const char* Kbuf) {
        const char* Ktbuf = Kbuf + 8192;   // bytes

        // ---- QK^T (swapped): S^T[kv][q]; lane owns column q = q5 ----
        f32x16 s0, s1;
        #pragma unroll
        for (int r = 0; r < 16; ++r) { s0[r] = 0.f; s1[r] = 0.f; }
        __builtin_amdgcn_s_setprio(1);
        #pragma unroll
        for (int kd = 0; kd < 4; ++kd) {
            const int cb = (kd * 32 + hi * 16) ^ swz;
            short8 kf0 = *(const short8*)(Kbuf + ro0 + cb);
            short8 kf1 = *(const short8*)(Kbuf + ro1 + cb);
            s0 = __builtin_amdgcn_mfma_f32_32x32x16_bf16(kf0, qB[kd], s0, 0, 0, 0);
            s1 = __builtin_amdgcn_mfma_f32_32x32x16_bf16(kf1, qB[kd], s1, 0, 0, 0);
        }
        __builtin_amdgcn_s_setprio(0);

        // ---- P = exp2(S) packed to bf16 A-fragments in-register; l on VALU ----
        u32x4 paw[4];
        PACK_P(s0, s1, paw, l_run);

        // ---- PV: V-frags from swizzled KT LDS ----
        __builtin_amdgcn_s_setprio(1);
        #pragma unroll
        for (int ks = 0; ks < 4; ++ks) {
            union { u32x4 u; short8 s; } pa; pa.u = paw[ks];
            const int cb = (ks * 32 + hi * 16) ^ swz;
            short8 vf0 = *(const short8*)(Ktbuf + ro0 + cb);
            short8 vf1 = *(const short8*)(Ktbuf + ro1 + cb);
            acc0 = __builtin_amdgcn_mfma_f32_32x32x16_bf16(pa.s, vf0, acc0, 0, 0, 0);
            acc1 = __builtin_amdgcn_mfma_f32_32x32x16_bf16(pa.s, vf1, acc1, 0, 0, 0);
        }
        __builtin_amdgcn_s_setprio(0);
    };

    STAGE(0, 0);
    for (int it = 0; it < NS / 128; ++it) {           // 16 sync points
        const int cur = it & 1;
        asm volatile("s_waitcnt vmcnt(0)" ::: "memory");
        __syncthreads();
        if (it < NS / 128 - 1) STAGE(cur ^ 1, (it + 1) * 128);   // flies during compute

        const char* base = (const char*)LDSA + cur * 32768;
        COMPUTE(base);            // kv sub-tile a
        COMPUTE(base + 16384);    // kv sub-tile b (same registers, serial)
    }

    // ---- epilogue: lane q5 holds hi-half of l(q-row q5); merge + redistribute ----
    const float lt = l_run + __shfl_xor(l_run, 32);   // full l for q-row q5
    const float inv = 1.0f / lt;
    #pragma unroll
    for (int r = 0; r < 16; ++r) {
        const int qr = (r & 3) + 8 * (r >> 2) + 4 * hi;
        const float invr = __shfl(inv, qr);           // l(qr) lives at lane qr
        float* orow = outp + ((size_t)b * NS + (qbase + qr)) * NHD + h * ND;
        orow[q5]      = acc0[r] * invr;
        orow[32 + q5] = acc1[r] * invr;
    }
}

extern "C" void kernel_launch(void* const* d_in, const int* in_sizes, int n_in,
                              void* d_out, int out_size, void* d_ws, size_t ws_size,
                              hipStream_t stream) {
    const float* xq = (const float*)d_in[0];
    const float* xk = (const float*)d_in[1];
    const float* Wq = (const float*)d_in[2];
    const float* bq = (const float*)d_in[3];
    const float* Wk = (const float*)d_in[4];
    const float* bk = (const float*)d_in[5];
    float* outp = (float*)d_out;

    // workspace layout (bf16 elements)
    unsigned short* Wqb = (unsigned short*)d_ws;          // 1024x1024
    unsigned short* Wkb = Wqb + 1048576;                  // 1024x1024
    unsigned short* Qb  = Wkb + 1048576;                  // [B][H][S][D]
    unsigned short* Kb  = Qb  + 8388608;                  // [B][H][S][D]
    unsigned short* KTb = Kb  + 8388608;                  // [B][H][D][S]

    // one-time opt-in for 160 KiB dynamic LDS (host-side, graph-capture safe)
    static bool lds_init = false;
    if (!lds_init) {
        hipFuncSetAttribute((const void*)proj_gemm5,
                            hipFuncAttributeMaxDynamicSharedMemorySize, 163840);
        lds_init = true;
    }

    cvt_w_bf16<<<1024, 256, 0, stream>>>(Wq, Wk, Wqb, Wkb);

    const float qscale = 0.125f * 1.4426950408889634f;   // D^-0.5 * log2(e)
    proj_gemm5<<<256, 512, 163840, stream>>>(xq, xk, Wqb, Wkb, bq, bk,
                                             Qb, Kb, KTb, qscale);

    // grid 512 x 512 threads = 2 blocks/CU (16 waves/CU); Bid = x + 8y + 128z linear
    attn_fused<<<dim3(8, 16, 4), 512, 0, stream>>>(Qb, Kb, KTb, outp);
}

// Round 9
// 136.594 us; speedup vs baseline: 1.0378x; 1.0378x over previous
//
#include <hip/hip_runtime.h>
#include <stdint.h>

// Problem constants
#define NB 4
#define NS 2048
#define NH 16
#define ND 64
#define NHD 1024   // H*D
#define NK 1024    // DQ = DK

typedef __attribute__((ext_vector_type(8))) short short8;
typedef __attribute__((ext_vector_type(4))) float f32x4;
typedef __attribute__((ext_vector_type(16))) float f32x16;
typedef __attribute__((ext_vector_type(4))) unsigned u32x4;

__device__ __forceinline__ unsigned short f2bf(float f) {
    union { float f; unsigned u; } v; v.f = f;
    return (unsigned short)((v.u + 0x7fffu + ((v.u >> 16) & 1u)) >> 16);  // RNE
}

__device__ __forceinline__ void gload_lds16(const unsigned short* g, unsigned short* l) {
    __builtin_amdgcn_global_load_lds(
        (const __attribute__((address_space(1))) void*)g,
        (__attribute__((address_space(3))) void*)l, 16, 0, 0);
}

__device__ __forceinline__ unsigned cvtpk(float lo, float hi) {
    unsigned r;
    asm volatile("v_cvt_pk_bf16_f32 %0, %1, %2" : "=v"(r) : "v"(lo), "v"(hi));
    return r;
}
__device__ __forceinline__ void plswap(unsigned& a, unsigned& b) {
    asm volatile("v_permlane32_swap_b32 %0, %1" : "+v"(a), "+v"(b));
}
// raw v_exp_f32: exact for our bounded inputs (|x| <= ~30), avoids libm fixup code
__device__ __forceinline__ float exp2_raw(float x) {
    float r;
    asm("v_exp_f32 %0, %1" : "=v"(r) : "v"(x));
    return r;
}

// ---------------- merged W cvt: both weight matrices in one launch ----------------
__global__ void cvt_w_bf16(const float* __restrict__ Wq, const float* __restrict__ Wk,
                           unsigned short* __restrict__ Wqb, unsigned short* __restrict__ Wkb) {
    const int n4 = (NK * NHD) / 4;   // per matrix
    const int stride = gridDim.x * blockDim.x;
    for (int i = blockIdx.x * blockDim.x + threadIdx.x; i < 2 * n4; i += stride) {
        const int m = i < n4 ? 0 : 1;
        const int j = m ? i - n4 : i;
        const float4 v = m ? ((const float4*)Wk)[j] : ((const float4*)Wq)[j];
        ushort4 o;
        o.x = f2bf(v.x); o.y = f2bf(v.y); o.z = f2bf(v.z); o.w = f2bf(v.w);
        if (m) ((ushort4*)Wkb)[j] = o; else ((ushort4*)Wqb)[j] = o;
    }
}

// ---------------- projection GEMM: 256x256 tile, BK=64, 8 waves, 4-phase interleave -------
// R7 base (best: proj ~54us) + R9 changes:
//  (a) p3 counted wait corrected vmcnt(20)->vmcnt(8): with 12 vm outstanding at p3 the old
//      wait was a NO-OP and B(it+1)'s landing relied on physical L2 latency (latent race).
//      vmcnt(8) = retire B(it+1)'s 4 gloads, keep A(it+2)'s 8 flat loads flying.
//  (b) p1 WRITEA and p3 vmcnt moved AFTER their phase's MFMA cluster (HK pattern: waits
//      between MFMA and barrier): the A-reg vmcnt wait + 16 cvtpk + ds_writes now overlap
//      this wave's MFMA drain and other waves' MFMA execution instead of blocking the
//      matrix pipe.  No data deps cross the move -> bit-identical output.
// R8 lesson: 128x512 retile regressed (B-prefetch distance collapsed); 256x256 is kept.
#define PH_SYNC() do { __builtin_amdgcn_s_barrier(); __builtin_amdgcn_sched_barrier(0); \
    asm volatile("s_waitcnt lgkmcnt(0)" ::: "memory"); __builtin_amdgcn_sched_barrier(0); } while (0)
#define PH_END()  do { __builtin_amdgcn_s_barrier(); __builtin_amdgcn_sched_barrier(0); } while (0)

#define RD_AF(MH, KK)                                                                     \
    _Pragma("unroll")                                                                     \
    for (int mi_ = 0; mi_ < 4; ++mi_) {                                                   \
        const int rowA_ = wm + (MH) * 64 + mi_ * 16 + lr;                                 \
        af[mi_] = *(const short8*)(Ab + (rowA_ << 7) + (((KK) * 64 + lg * 16) ^ swzr));   \
    }
#define RD_BF(KK)                                                                         \
    _Pragma("unroll")                                                                     \
    for (int ni_ = 0; ni_ < 4; ++ni_) {                                                   \
        const int rowB_ = wn + ni_ * 16 + lr;                                             \
        bfr[ni_] = *(const short8*)(Bb + (rowB_ << 7) + (((KK) * 64 + lg * 16) ^ swzr));  \
    }
#define DO_MFMA(MH)                                                                       \
    do {                                                                                  \
        __builtin_amdgcn_s_setprio(1);                                                    \
        _Pragma("unroll")                                                                 \
        for (int mi_ = 0; mi_ < 4; ++mi_)                                                 \
            _Pragma("unroll")                                                             \
            for (int ni_ = 0; ni_ < 4; ++ni_)                                             \
                acc[(MH) * 4 + mi_][ni_] = __builtin_amdgcn_mfma_f32_16x16x32_bf16(       \
                    af[mi_], bfr[ni_], acc[(MH) * 4 + mi_][ni_], 0, 0, 0);                \
        __builtin_amdgcn_s_setprio(0);                                                    \
    } while (0)

__global__ __launch_bounds__(512, 2) void proj_gemm3(
    const float* __restrict__ Xq,
    const float* __restrict__ Xk,
    const unsigned short* __restrict__ Wqb,
    const unsigned short* __restrict__ Wkb,
    const float* __restrict__ bqv,
    const float* __restrict__ bkv,
    unsigned short* __restrict__ Qo,
    unsigned short* __restrict__ Ko,
    unsigned short* __restrict__ KTo,
    float qscale)
{
    // dynamic LDS, 128 KiB: A0 @0, A1 @32K, B0 @64K, B1 @96K  (each 256x64 bf16, swizzled)
    extern __shared__ __attribute__((aligned(16))) char smem[];

    const int bid = blockIdx.x;
    const int wg = (bid & 7) * 32 + (bid >> 3);
    const int mp = wg >> 2;            // 0..63  (0..31 = Q rows, 32..63 = K rows)
    const int nb = wg & 3;             // 0..3
    const int which = mp >> 5;
    const long bm = (long)(mp & 31) * 256;
    const long bn = (long)nb * 256;

    const float* A32         = which ? Xk : Xq;
    const unsigned short* Wt = which ? Wkb : Wqb;
    const float* bias        = which ? bkv : bqv;
    unsigned short* outp     = which ? Ko : Qo;
    unsigned short* outT     = which ? KTo : nullptr;
    const float scale        = which ? 1.0f : qscale;

    const int t = threadIdx.x;
    const int lane = t & 63;
    const int w = t >> 6;                       // 0..7
    const int wm = (w >> 1) * 64, wn = (w & 1) * 64;
    // NOTE: wave tiling identical to R7: wm = (w>>2)*128? — see below, kept as R7.
    const int wm7 = (w >> 2) * 128, wn7 = (w & 3) * 64;
    (void)wm; (void)wn;

    const int lr = lane & 15, lg = lane >> 4;
    const int swzr = (lr & 7) << 4;

    f32x4 acc[8][4];
    #pragma unroll
    for (int i = 0; i < 8; ++i)
        #pragma unroll
        for (int jj = 0; jj < 4; ++jj) acc[i][jj] = (f32x4){0.f, 0.f, 0.f, 0.f};

    float4 aset[8];   // single in-flight fp32 A set (issued t p2, written t+1 p1)

    auto LOADA = [&](int k0) {
        #pragma unroll
        for (int c = 0; c < 4; ++c) {
            const int u2 = c * 512 + t;
            const int row = u2 >> 3, c8 = u2 & 7;
            const float* src = A32 + (bm + row) * (long)NK + k0 + c8 * 8;
            aset[2 * c]     = *(const float4*)src;
            aset[2 * c + 1] = *(const float4*)(src + 4);
        }
    };
    auto WRITEA = [&](int buf) {
        char* Ad = smem + buf * 32768;
        #pragma unroll
        for (int c = 0; c < 4; ++c) {
            const int u2 = c * 512 + t;
            const int row = u2 >> 3;
            const int cbyte = ((u2 & 7) << 4) ^ ((row & 7) << 4);   // T2 swizzle
            u32x4 wv;
            wv[0] = cvtpk(aset[2 * c].x, aset[2 * c].y);
            wv[1] = cvtpk(aset[2 * c].z, aset[2 * c].w);
            wv[2] = cvtpk(aset[2 * c + 1].x, aset[2 * c + 1].y);
            wv[3] = cvtpk(aset[2 * c + 1].z, aset[2 * c + 1].w);
            *(u32x4*)(Ad + (row << 7) + cbyte) = wv;
        }
    };
    const int scolB = (((lane & 7) ^ (lane >> 3)) << 3);   // pre-swizzled global source
    auto BGLOAD = [&](int k0, int buf) {
        unsigned short* Bd = (unsigned short*)(smem + 65536 + buf * 32768);
        #pragma unroll
        for (int c = 0; c < 4; ++c) {
            const int rowB = c * 64 + w * 8 + (lane >> 3);
            gload_lds16(Wt + (bn + rowB) * (long)NK + k0 + scolB,
                        Bd + (size_t)(c * 64 + w * 8) * 64);
        }
    };

    // ---- prologue: B(0), A(0) staged; A(1) in flight ----
    BGLOAD(0, 0);                                    // 4 vm
    asm volatile("" ::: "memory");
    LOADA(0);                                        // 8 vm
    asm volatile("" ::: "memory");
    WRITEA(0);                                       // compiler vmcnt drains B(0)+A(0)
    __builtin_amdgcn_sched_barrier(0);
    LOADA(64);                                       // A(1), 8 vm, stays in flight
    asm volatile("s_waitcnt lgkmcnt(0)" ::: "memory");
    __builtin_amdgcn_s_barrier();
    __builtin_amdgcn_sched_barrier(0);

    {
        const int wm = wm7, wn = wn7;   // R7 wave tiling: 128m x 64n per wave
        for (int it = 0; it < 16; ++it) {
            const int cur = it & 1;
            const char* Ab = (const char*)smem + cur * 32768;
            const char* Bb = (const char*)smem + 65536 + cur * 32768;
            short8 af[4], bfr[4];

            // ---- phase 0: mh=0, kk=0; issue B(it+1) ----
            RD_BF(0); RD_AF(0, 0);
            if (it + 1 < 16) BGLOAD((it + 1) * 64, cur ^ 1);
            PH_SYNC(); DO_MFMA(0); PH_END();

            // ---- phase 1: mh=1, kk=0; MFMA first, then convert+write A(it+1) ----
            RD_AF(1, 0);
            PH_SYNC();
            DO_MFMA(1);
            __builtin_amdgcn_sched_barrier(0);
            if (it + 1 < 16) WRITEA(cur ^ 1);   // A-vmcnt + cvtpk hidden under MFMA drain
            PH_END();

            // ---- phase 2: mh=0, kk=1; issue A(it+2) ----
            RD_BF(1); RD_AF(0, 1);
            if (it + 2 < 16) LOADA((it + 2) * 64);
            PH_SYNC(); DO_MFMA(0); PH_END();

            // ---- phase 3: mh=1, kk=1; MFMA first, then retire B(it+1) ----
            RD_AF(1, 1);
            PH_SYNC();
            DO_MFMA(1);
            __builtin_amdgcn_sched_barrier(0);
            if (it + 2 < 16)      asm volatile("s_waitcnt vmcnt(8)" ::: "memory");
            else if (it + 1 < 16) asm volatile("s_waitcnt vmcnt(0)" ::: "memory");
            PH_END();
        }
    }

    // ---- epilogue: bias + scale + bf16 store, row-burst order (R7) ----
    // Wave's n-slice is one head: h const, d = ni*16+lr spans 0..63.
    {
        const int wm = wm7, wn = wn7;
        const int h = (int)((bn + wn) >> 6);
        float bvv[4];
        #pragma unroll
        for (int ni = 0; ni < 4; ++ni) bvv[ni] = bias[(int)bn + wn + ni * 16 + lr];
        #pragma unroll
        for (int mi = 0; mi < 8; ++mi) {
            const int m0 = (int)bm + wm + mi * 16 + lg * 4;
            const int b = m0 >> 11, s0 = m0 & 2047;
            unsigned short vv[4][4];
            #pragma unroll
            for (int ni = 0; ni < 4; ++ni)
                #pragma unroll
                for (int r = 0; r < 4; ++r)
                    vv[ni][r] = f2bf((acc[mi][ni][r] + bvv[ni]) * scale);
            unsigned short* orow = outp + (((size_t)(b * NH + h)) * NS + s0) * ND;
            #pragma unroll
            for (int r = 0; r < 4; ++r)
                #pragma unroll
                for (int ni = 0; ni < 4; ++ni)
                    orow[(size_t)r * ND + ni * 16 + lr] = vv[ni][r];
            if (outT) {
                #pragma unroll
                for (int ni = 0; ni < 4; ++ni) {
                    const int d = ni * 16 + lr;
                    ushort4 tv; tv.x = vv[ni][0]; tv.y = vv[ni][1]; tv.z = vv[ni][2]; tv.w = vv[ni][3];
                    *(ushort4*)&outT[(((size_t)(b * NH + h)) * ND + d) * NS + s0] = tv;
                }
            }
        }
    }
}

// max-free P pack + f32 row-half-sum: paw = bf16 A-frags of exp2(S); lsum += sum(P)
// Numerics: |S_log2| <= ~12 (input-licensed), exp2(S) in [2^-12, 2^12] — no max needed.
#define PACK_P(s0, s1, paw, lsum)                                              \
    do {                                                                       \
        _Pragma("unroll")                                                      \
        for (int tt_ = 0; tt_ < 2; ++tt_) {                                    \
            unsigned c_[8];                                                    \
            _Pragma("unroll")                                                  \
            for (int j_ = 0; j_ < 8; ++j_) {                                   \
                const float plo_ = exp2_raw(tt_ ? s1[2 * j_]     : s0[2 * j_]);   \
                const float phi_ = exp2_raw(tt_ ? s1[2 * j_ + 1] : s0[2 * j_ + 1]); \
                (lsum) += plo_ + phi_;                                         \
                c_[j_] = cvtpk(plo_, phi_);                                    \
            }                                                                  \
            plswap(c_[0], c_[2]); plswap(c_[1], c_[3]);                        \
            plswap(c_[4], c_[6]); plswap(c_[5], c_[7]);                        \
            paw[2 * tt_]     = (u32x4){c_[0], c_[1], c_[2], c_[3]};            \
            paw[2 * tt_ + 1] = (u32x4){c_[4], c_[5], c_[6], c_[7]};            \
        }                                                                      \
    } while (0)

// ---------------- fused flash attention: 8-wave blocks, KVBLK=128 (2 sub-tiles/sync) ----
// Proven 82.0us version — frozen (structural plateau; LDS b128 reads at the measured
// ~12cyc throughput ceiling, matrix+LDS+VALU pipe mix saturated; isolated grafts
// measured null/negative in R2-R4).
__global__ __launch_bounds__(512, 4) void attn_fused(
    const unsigned short* __restrict__ Qb,
    const unsigned short* __restrict__ Kb,
    const unsigned short* __restrict__ KTb,
    float* __restrict__ outp)
{
    // 2 buffers x { Ka[64][64] @0, KTa @8K, Kb[64][64] @16K, KTb @24K }, rows XOR-swizzled
    __shared__ __attribute__((aligned(16))) unsigned short LDSA[2 * 4 * 4096];  // 64 KiB

    const int t = threadIdx.x;
    const int lane = t & 63;
    const int wq = t >> 6;          // 0..7
    const int q5 = lane & 31;
    const int hi = lane >> 5;

    // XCD-aware remap: all 8 q-blocks of one (b,h) share an XCD => K/KT L2-resident.
    const int Bid = blockIdx.x + 8 * blockIdx.y + 128 * blockIdx.z;   // 0..511 linear
    const int xcd = Bid & 7;
    const int wIdx = Bid >> 3;      // 0..63
    const int qblk = wIdx & 7;      // 8 q-blocks x 256 q
    const int g = xcd * 8 + (wIdx >> 3);
    const int h = g & 15, b = g >> 4;
    const int qbase = qblk * 256 + wq * 32;

    const unsigned short* Qh  = Qb  + ((size_t)(b * NH + h)) * NS * ND;
    const unsigned short* Kh  = Kb  + ((size_t)(b * NH + h)) * NS * ND;
    const unsigned short* KTh = KTb + ((size_t)(b * NH + h)) * ND * NS;

    // Q fragments (B-operand): col = q5, k(d) = kd*16 + hi*8 + e
    short8 qB[4];
    {
        const unsigned short* Qrow = Qh + (size_t)(qbase + q5) * ND;
        #pragma unroll
        for (int kd = 0; kd < 4; ++kd)
            qB[kd] = *(const short8*)&Qrow[kd * 16 + hi * 8];
    }

    // staging: one 1KB chunk per thread per array (8 waves cover 8 chunks)
    const int srow = wq * 8 + (lane >> 3);
    const int scol = ((((lane & 7) << 4) ^ ((srow & 7) << 4)) >> 1);

    f32x16 acc0, acc1;
    float l_run = 0.f;
    #pragma unroll
    for (int r = 0; r < 16; ++r) { acc0[r] = 0.f; acc1[r] = 0.f; }

    const int swz = (q5 & 7) << 4;
    const int ro0 = q5 * 128, ro1 = ro0 + 4096;

    auto STAGE = [&](int buf, int kt /*kv base, mult of 128*/) {
        unsigned short* Bd = &LDSA[buf * 16384];
        gload_lds16(Kh  + (size_t)(kt + srow) * ND + scol,        Bd         + wq * 512);
        gload_lds16(KTh + (size_t)srow * NS + kt + scol,          Bd + 4096  + wq * 512);
        gload_lds16(Kh  + (size_t)(kt + 64 + srow) * ND + scol,   Bd + 8192  + wq * 512);
        gload_lds16(KTh + (size_t)srow * NS + (kt + 64) + scol,   Bd + 12288 + wq * 512);
    };

    // one 64-kv sub-tile: QK^T (swapped) -> PACK -> PV, all registers local
    auto COMPUTE = [&](const char* Kbuf) {
        const char* Ktbuf = Kbuf + 8192;   // bytes

        // ---- QK^T (swapped): S^T[kv][q]; lane owns column q = q5 ----
        f32x16 s0, s1;
        #pragma unroll
        for (int r = 0; r < 16; ++r) { s0[r] = 0.f; s1[r] = 0.f; }
        __builtin_amdgcn_s_setprio(1);
        #pragma unroll
        for (int kd = 0; kd < 4; ++kd) {
            const int cb = (kd * 32 + hi * 16) ^ swz;
            short8 kf0 = *(const short8*)(Kbuf + ro0 + cb);
            short8 kf1 = *(const short8*)(Kbuf + ro1 + cb);
            s0 = __builtin_amdgcn_mfma_f32_32x32x16_bf16(kf0, qB[kd], s0, 0, 0, 0);
            s1 = __builtin_amdgcn_mfma_f32_32x32x16_bf16(kf1, qB[kd], s1, 0, 0, 0);
        }
        __builtin_amdgcn_s_setprio(0);

        // ---- P = exp2(S) packed to bf16 A-fragments in-register; l on VALU ----
        u32x4 paw[4];
        PACK_P(s0, s1, paw, l_run);

        // ---- PV: V-frags from swizzled KT LDS ----
        __builtin_amdgcn_s_setprio(1);
        #pragma unroll
        for (int ks = 0; ks < 4; ++ks) {
            union { u32x4 u; short8 s; } pa; pa.u = paw[ks];
            const int cb = (ks * 32 + hi * 16) ^ swz;
            short8 vf0 = *(const short8*)(Ktbuf + ro0 + cb);
            short8 vf1 = *(const short8*)(Ktbuf + ro1 + cb);
            acc0 = __builtin_amdgcn_mfma_f32_32x32x16_bf16(pa.s, vf0, acc0, 0, 0, 0);
            acc1 = __builtin_amdgcn_mfma_f32_32x32x16_bf16(pa.s, vf1, acc1, 0, 0, 0);
        }
        __builtin_amdgcn_s_setprio(0);
    };

    STAGE(0, 0);
    for (int it = 0; it < NS / 128; ++it) {           // 16 sync points
        const int cur = it & 1;
        asm volatile("s_waitcnt vmcnt(0)" ::: "memory");
        __syncthreads();
        if (it < NS / 128 - 1) STAGE(cur ^ 1, (it + 1) * 128);   // flies during compute

        const char* base = (const char*)LDSA + cur * 32768;
        COMPUTE(base);            // kv sub-tile a
        COMPUTE(base + 16384);    // kv sub-tile b (same registers, serial)
    }

    // ---- epilogue: lane q5 holds hi-half of l(q-row q5); merge + redistribute ----
    const float lt = l_run + __shfl_xor(l_run, 32);   // full l for q-row q5
    const float inv = 1.0f / lt;
    #pragma unroll
    for (int r = 0; r < 16; ++r) {
        const int qr = (r & 3) + 8 * (r >> 2) + 4 * hi;
        const float invr = __shfl(inv, qr);           // l(qr) lives at lane qr
        float* orow = outp + ((size_t)b * NS + (qbase + qr)) * NHD + h * ND;
        orow[q5]      = acc0[r] * invr;
        orow[32 + q5] = acc1[r] * invr;
    }
}

extern "C" void kernel_launch(void* const* d_in, const int* in_sizes, int n_in,
                              void* d_out, int out_size, void* d_ws, size_t ws_size,
                              hipStream_t stream) {
    const float* xq = (const float*)d_in[0];
    const float* xk = (const float*)d_in[1];
    const float* Wq = (const float*)d_in[2];
    const float* bq = (const float*)d_in[3];
    const float* Wk = (const float*)d_in[4];
    const float* bk = (const float*)d_in[5];
    float* outp = (float*)d_out;

    // workspace layout (bf16 elements)
    unsigned short* Wqb = (unsigned short*)d_ws;          // 1024x1024
    unsigned short* Wkb = Wqb + 1048576;                  // 1024x1024
    unsigned short* Qb  = Wkb + 1048576;                  // [B][H][S][D]
    unsigned short* Kb  = Qb  + 8388608;                  // [B][H][S][D]
    unsigned short* KTb = Kb  + 8388608;                  // [B][H][D][S]

    // one-time opt-in for 128 KiB dynamic LDS (host-side, graph-capture safe)
    static bool lds_init = false;
    if (!lds_init) {
        hipFuncSetAttribute((const void*)proj_gemm3,
                            hipFuncAttributeMaxDynamicSharedMemorySize, 131072);
        lds_init = true;
    }

    cvt_w_bf16<<<1024, 256, 0, stream>>>(Wq, Wk, Wqb, Wkb);

    const float qscale = 0.125f * 1.4426950408889634f;   // D^-0.5 * log2(e)
    proj_gemm3<<<256, 512, 131072, stream>>>(xq, xk, Wqb, Wkb, bq, bk,
                                             Qb, Kb, KTb, qscale);

    // grid 512 x 512 threads = 2 blocks/CU (16 waves/CU); Bid = x + 8y + 128z linear
    attn_fused<<<dim3(8, 16, 4), 512, 0, stream>>>(Qb, Kb, KTb, outp);
}

// Round 10
// 132.890 us; speedup vs baseline: 1.0668x; 1.0279x over previous
//
#include <hip/hip_runtime.h>
#include <stdint.h>

// Problem constants
#define NB 4
#define NS 2048
#define NH 16
#define ND 64
#define NHD 1024   // H*D
#define NK 1024    // DQ = DK

typedef __attribute__((ext_vector_type(8))) short short8;
typedef __attribute__((ext_vector_type(4))) float f32x4;
typedef __attribute__((ext_vector_type(16))) float f32x16;
typedef __attribute__((ext_vector_type(4))) unsigned u32x4;

__device__ __forceinline__ unsigned short f2bf(float f) {
    union { float f; unsigned u; } v; v.f = f;
    return (unsigned short)((v.u + 0x7fffu + ((v.u >> 16) & 1u)) >> 16);  // RNE
}

__device__ __forceinline__ void gload_lds16(const unsigned short* g, unsigned short* l) {
    __builtin_amdgcn_global_load_lds(
        (const __attribute__((address_space(1))) void*)g,
        (__attribute__((address_space(3))) void*)l, 16, 0, 0);
}

__device__ __forceinline__ unsigned cvtpk(float lo, float hi) {
    unsigned r;
    asm volatile("v_cvt_pk_bf16_f32 %0, %1, %2" : "=v"(r) : "v"(lo), "v"(hi));
    return r;
}
__device__ __forceinline__ void plswap(unsigned& a, unsigned& b) {
    asm volatile("v_permlane32_swap_b32 %0, %1" : "+v"(a), "+v"(b));
}
// raw v_exp_f32: exact for our bounded inputs (|x| <= ~30), avoids libm fixup code
__device__ __forceinline__ float exp2_raw(float x) {
    float r;
    asm("v_exp_f32 %0, %1" : "=v"(r) : "v"(x));
    return r;
}

// ---------------- merged W cvt: both weight matrices in one launch ----------------
__global__ void cvt_w_bf16(const float* __restrict__ Wq, const float* __restrict__ Wk,
                           unsigned short* __restrict__ Wqb, unsigned short* __restrict__ Wkb) {
    const int n4 = (NK * NHD) / 4;   // per matrix
    const int stride = gridDim.x * blockDim.x;
    for (int i = blockIdx.x * blockDim.x + threadIdx.x; i < 2 * n4; i += stride) {
        const int m = i < n4 ? 0 : 1;
        const int j = m ? i - n4 : i;
        const float4 v = m ? ((const float4*)Wk)[j] : ((const float4*)Wq)[j];
        ushort4 o;
        o.x = f2bf(v.x); o.y = f2bf(v.y); o.z = f2bf(v.z); o.w = f2bf(v.w);
        if (m) ((ushort4*)Wkb)[j] = o; else ((ushort4*)Wqb)[j] = o;
    }
}

// ---------------- projection GEMM: 256x256 tile, BK=64, 8 waves, 1 barrier/K-step --------
// R10: the 8 per-phase barriers per K-step guard NOTHING — within an iteration all phases
// read A[cur]/B[cur] and write only A[cur^1]/B[cur^1] (no intra-iteration cross-wave
// hazard).  The only required rendezvous is once per K-step: vmcnt(8) (land own B(it+1),
// keep A(it+2)'s 8 flat loads flying) + lgkmcnt(0) (drain own WRITEA ds_writes) + barrier.
// Everything else free-runs under compiler scheduling (fine-grained lgkmcnt for ds_read->
// MFMA is compiler-emitted).  MFMA order per acc unchanged (kk0 m0,m1; kk1 m0,m1) ->
// bit-identical output.  R9's waits-after-MFMA and counted vmcnt retained in spirit;
// R8 lesson: keep 256x256 (B-prefetch distance); R5: conflicts=0, fetch=inputs-once.

#define RD_AF(MH, KK)                                                                     \
    _Pragma("unroll")                                                                     \
    for (int mi_ = 0; mi_ < 4; ++mi_) {                                                   \
        const int rowA_ = wm + (MH) * 64 + mi_ * 16 + lr;                                 \
        af[mi_] = *(const short8*)(Ab + (rowA_ << 7) + (((KK) * 64 + lg * 16) ^ swzr));   \
    }
#define RD_BF(KK)                                                                         \
    _Pragma("unroll")                                                                     \
    for (int ni_ = 0; ni_ < 4; ++ni_) {                                                   \
        const int rowB_ = wn + ni_ * 16 + lr;                                             \
        bfr[ni_] = *(const short8*)(Bb + (rowB_ << 7) + (((KK) * 64 + lg * 16) ^ swzr));  \
    }
#define DO_MFMA(MH)                                                                       \
    do {                                                                                  \
        __builtin_amdgcn_s_setprio(1);                                                    \
        _Pragma("unroll")                                                                 \
        for (int mi_ = 0; mi_ < 4; ++mi_)                                                 \
            _Pragma("unroll")                                                             \
            for (int ni_ = 0; ni_ < 4; ++ni_)                                             \
                acc[(MH) * 4 + mi_][ni_] = __builtin_amdgcn_mfma_f32_16x16x32_bf16(       \
                    af[mi_], bfr[ni_], acc[(MH) * 4 + mi_][ni_], 0, 0, 0);                \
        __builtin_amdgcn_s_setprio(0);                                                    \
    } while (0)

__global__ __launch_bounds__(512, 2) void proj_gemm3(
    const float* __restrict__ Xq,
    const float* __restrict__ Xk,
    const unsigned short* __restrict__ Wqb,
    const unsigned short* __restrict__ Wkb,
    const float* __restrict__ bqv,
    const float* __restrict__ bkv,
    unsigned short* __restrict__ Qo,
    unsigned short* __restrict__ Ko,
    unsigned short* __restrict__ KTo,
    float qscale)
{
    // dynamic LDS, 128 KiB: A0 @0, A1 @32K, B0 @64K, B1 @96K  (each 256x64 bf16, swizzled)
    extern __shared__ __attribute__((aligned(16))) char smem[];

    const int bid = blockIdx.x;
    const int wg = (bid & 7) * 32 + (bid >> 3);
    const int mp = wg >> 2;            // 0..63  (0..31 = Q rows, 32..63 = K rows)
    const int nb = wg & 3;             // 0..3
    const int which = mp >> 5;
    const long bm = (long)(mp & 31) * 256;
    const long bn = (long)nb * 256;

    const float* A32         = which ? Xk : Xq;
    const unsigned short* Wt = which ? Wkb : Wqb;
    const float* bias        = which ? bkv : bqv;
    unsigned short* outp     = which ? Ko : Qo;
    unsigned short* outT     = which ? KTo : nullptr;
    const float scale        = which ? 1.0f : qscale;

    const int t = threadIdx.x;
    const int lane = t & 63;
    const int w = t >> 6;                       // 0..7
    const int wm = (w >> 2) * 128, wn = (w & 3) * 64;   // wave tile 128m x 64n
    const int lr = lane & 15, lg = lane >> 4;
    const int swzr = (lr & 7) << 4;

    f32x4 acc[8][4];
    #pragma unroll
    for (int i = 0; i < 8; ++i)
        #pragma unroll
        for (int jj = 0; jj < 4; ++jj) acc[i][jj] = (f32x4){0.f, 0.f, 0.f, 0.f};

    float4 aset[8];   // single in-flight fp32 A set

    auto LOADA = [&](int k0) {
        #pragma unroll
        for (int c = 0; c < 4; ++c) {
            const int u2 = c * 512 + t;
            const int row = u2 >> 3, c8 = u2 & 7;
            const float* src = A32 + (bm + row) * (long)NK + k0 + c8 * 8;
            aset[2 * c]     = *(const float4*)src;
            aset[2 * c + 1] = *(const float4*)(src + 4);
        }
    };
    auto WRITEA = [&](int buf) {
        char* Ad = smem + buf * 32768;
        #pragma unroll
        for (int c = 0; c < 4; ++c) {
            const int u2 = c * 512 + t;
            const int row = u2 >> 3;
            const int cbyte = ((u2 & 7) << 4) ^ ((row & 7) << 4);   // T2 swizzle
            u32x4 wv;
            wv[0] = cvtpk(aset[2 * c].x, aset[2 * c].y);
            wv[1] = cvtpk(aset[2 * c].z, aset[2 * c].w);
            wv[2] = cvtpk(aset[2 * c + 1].x, aset[2 * c + 1].y);
            wv[3] = cvtpk(aset[2 * c + 1].z, aset[2 * c + 1].w);
            *(u32x4*)(Ad + (row << 7) + cbyte) = wv;
        }
    };
    const int scolB = (((lane & 7) ^ (lane >> 3)) << 3);   // pre-swizzled global source
    auto BGLOAD = [&](int k0, int buf) {
        unsigned short* Bd = (unsigned short*)(smem + 65536 + buf * 32768);
        #pragma unroll
        for (int c = 0; c < 4; ++c) {
            const int rowB = c * 64 + w * 8 + (lane >> 3);
            gload_lds16(Wt + (bn + rowB) * (long)NK + k0 + scolB,
                        Bd + (size_t)(c * 64 + w * 8) * 64);
        }
    };

    // ---- prologue: B(0), A(0) staged; A(1) in flight ----
    BGLOAD(0, 0);                                    // 4 vm
    asm volatile("" ::: "memory");
    LOADA(0);                                        // 8 vm
    asm volatile("" ::: "memory");
    WRITEA(0);                                       // compiler vmcnt drains B(0)+A(0)
    __builtin_amdgcn_sched_barrier(0);
    LOADA(64);                                       // A(1), 8 vm, stays in flight
    asm volatile("s_waitcnt lgkmcnt(0)" ::: "memory");
    __builtin_amdgcn_s_barrier();
    __builtin_amdgcn_sched_barrier(0);

    for (int it = 0; it < 16; ++it) {
        const int cur = it & 1;
        const char* Ab = (const char*)smem + cur * 32768;
        const char* Bb = (const char*)smem + 65536 + cur * 32768;
        short8 af[4], bfr[4];

        // issue next B-tile DMA first (max latency cover; lands by next-iter barrier)
        if (it + 1 < 16) BGLOAD((it + 1) * 64, cur ^ 1);

        // --- free-running compute body: no intra-iteration barriers ---
        RD_BF(0); RD_AF(0, 0);
        DO_MFMA(0);
        if (it + 1 < 16) WRITEA(cur ^ 1);   // implicit ordered vmcnt retires A(it+1) only
        RD_AF(1, 0);
        DO_MFMA(1);
        RD_BF(1); RD_AF(0, 1);
        DO_MFMA(0);
        if (it + 2 < 16) LOADA((it + 2) * 64);
        RD_AF(1, 1);
        DO_MFMA(1);

        // --- single rendezvous per K-step ---
        if (it + 2 < 16)      asm volatile("s_waitcnt vmcnt(8)" ::: "memory");  // B(it+1) landed, A(it+2) flying
        else                  asm volatile("s_waitcnt vmcnt(0)" ::: "memory");  // tail drain
        asm volatile("s_waitcnt lgkmcnt(0)" ::: "memory");                      // own ds_writes visible
        __builtin_amdgcn_s_barrier();
        __builtin_amdgcn_sched_barrier(0);
    }

    // ---- epilogue: bias + scale + bf16 store, row-burst order (R7) ----
    // Wave's n-slice is one head: h const, d = ni*16+lr spans 0..63.
    const int h = (int)((bn + wn) >> 6);
    float bvv[4];
    #pragma unroll
    for (int ni = 0; ni < 4; ++ni) bvv[ni] = bias[(int)bn + wn + ni * 16 + lr];
    #pragma unroll
    for (int mi = 0; mi < 8; ++mi) {
        const int m0 = (int)bm + wm + mi * 16 + lg * 4;
        const int b = m0 >> 11, s0 = m0 & 2047;
        unsigned short vv[4][4];
        #pragma unroll
        for (int ni = 0; ni < 4; ++ni)
            #pragma unroll
            for (int r = 0; r < 4; ++r)
                vv[ni][r] = f2bf((acc[mi][ni][r] + bvv[ni]) * scale);
        unsigned short* orow = outp + (((size_t)(b * NH + h)) * NS + s0) * ND;
        #pragma unroll
        for (int r = 0; r < 4; ++r)
            #pragma unroll
            for (int ni = 0; ni < 4; ++ni)
                orow[(size_t)r * ND + ni * 16 + lr] = vv[ni][r];
        if (outT) {
            #pragma unroll
            for (int ni = 0; ni < 4; ++ni) {
                const int d = ni * 16 + lr;
                ushort4 tv; tv.x = vv[ni][0]; tv.y = vv[ni][1]; tv.z = vv[ni][2]; tv.w = vv[ni][3];
                *(ushort4*)&outT[(((size_t)(b * NH + h)) * ND + d) * NS + s0] = tv;
            }
        }
    }
}

// max-free P pack + f32 row-half-sum: paw = bf16 A-frags of exp2(S); lsum += sum(P)
// Numerics: |S_log2| <= ~12 (input-licensed), exp2(S) in [2^-12, 2^12] — no max needed.
#define PACK_P(s0, s1, paw, lsum)                                              \
    do {                                                                       \
        _Pragma("unroll")                                                      \
        for (int tt_ = 0; tt_ < 2; ++tt_) {                                    \
            unsigned c_[8];                                                    \
            _Pragma("unroll")                                                  \
            for (int j_ = 0; j_ < 8; ++j_) {                                   \
                const float plo_ = exp2_raw(tt_ ? s1[2 * j_]     : s0[2 * j_]);   \
                const float phi_ = exp2_raw(tt_ ? s1[2 * j_ + 1] : s0[2 * j_ + 1]); \
                (lsum) += plo_ + phi_;                                         \
                c_[j_] = cvtpk(plo_, phi_);                                    \
            }                                                                  \
            plswap(c_[0], c_[2]); plswap(c_[1], c_[3]);                        \
            plswap(c_[4], c_[6]); plswap(c_[5], c_[7]);                        \
            paw[2 * tt_]     = (u32x4){c_[0], c_[1], c_[2], c_[3]};            \
            paw[2 * tt_ + 1] = (u32x4){c_[4], c_[5], c_[6], c_[7]};            \
        }                                                                      \
    } while (0)

// ---------------- fused flash attention: 8-wave blocks, KVBLK=128 (2 sub-tiles/sync) ----
// Proven 82.0us version — frozen (structural plateau; matrix+LDS+VALU pipe mix saturated;
// isolated grafts measured null/negative in R2-R4).
__global__ __launch_bounds__(512, 4) void attn_fused(
    const unsigned short* __restrict__ Qb,
    const unsigned short* __restrict__ Kb,
    const unsigned short* __restrict__ KTb,
    float* __restrict__ outp)
{
    // 2 buffers x { Ka[64][64] @0, KTa @8K, Kb[64][64] @16K, KTb @24K }, rows XOR-swizzled
    __shared__ __attribute__((aligned(16))) unsigned short LDSA[2 * 4 * 4096];  // 64 KiB

    const int t = threadIdx.x;
    const int lane = t & 63;
    const int wq = t >> 6;          // 0..7
    const int q5 = lane & 31;
    const int hi = lane >> 5;

    // XCD-aware remap: all 8 q-blocks of one (b,h) share an XCD => K/KT L2-resident.
    const int Bid = blockIdx.x + 8 * blockIdx.y + 128 * blockIdx.z;   // 0..511 linear
    const int xcd = Bid & 7;
    const int wIdx = Bid >> 3;      // 0..63
    const int qblk = wIdx & 7;      // 8 q-blocks x 256 q
    const int g = xcd * 8 + (wIdx >> 3);
    const int h = g & 15, b = g >> 4;
    const int qbase = qblk * 256 + wq * 32;

    const unsigned short* Qh  = Qb  + ((size_t)(b * NH + h)) * NS * ND;
    const unsigned short* Kh  = Kb  + ((size_t)(b * NH + h)) * NS * ND;
    const unsigned short* KTh = KTb + ((size_t)(b * NH + h)) * ND * NS;

    // Q fragments (B-operand): col = q5, k(d) = kd*16 + hi*8 + e
    short8 qB[4];
    {
        const unsigned short* Qrow = Qh + (size_t)(qbase + q5) * ND;
        #pragma unroll
        for (int kd = 0; kd < 4; ++kd)
            qB[kd] = *(const short8*)&Qrow[kd * 16 + hi * 8];
    }

    // staging: one 1KB chunk per thread per array (8 waves cover 8 chunks)
    const int srow = wq * 8 + (lane >> 3);
    const int scol = ((((lane & 7) << 4) ^ ((srow & 7) << 4)) >> 1);

    f32x16 acc0, acc1;
    float l_run = 0.f;
    #pragma unroll
    for (int r = 0; r < 16; ++r) { acc0[r] = 0.f; acc1[r] = 0.f; }

    const int swz = (q5 & 7) << 4;
    const int ro0 = q5 * 128, ro1 = ro0 + 4096;

    auto STAGE = [&](int buf, int kt /*kv base, mult of 128*/) {
        unsigned short* Bd = &LDSA[buf * 16384];
        gload_lds16(Kh  + (size_t)(kt + srow) * ND + scol,        Bd         + wq * 512);
        gload_lds16(KTh + (size_t)srow * NS + kt + scol,          Bd + 4096  + wq * 512);
        gload_lds16(Kh  + (size_t)(kt + 64 + srow) * ND + scol,   Bd + 8192  + wq * 512);
        gload_lds16(KTh + (size_t)srow * NS + (kt + 64) + scol,   Bd + 12288 + wq * 512);
    };

    // one 64-kv sub-tile: QK^T (swapped) -> PACK -> PV, all registers local
    auto COMPUTE = [&](const char* Kbuf) {
        const char* Ktbuf = Kbuf + 8192;   // bytes

        // ---- QK^T (swapped): S^T[kv][q]; lane owns column q = q5 ----
        f32x16 s0, s1;
        #pragma unroll
        for (int r = 0; r < 16; ++r) { s0[r] = 0.f; s1[r] = 0.f; }
        __builtin_amdgcn_s_setprio(1);
        #pragma unroll
        for (int kd = 0; kd < 4; ++kd) {
            const int cb = (kd * 32 + hi * 16) ^ swz;
            short8 kf0 = *(const short8*)(Kbuf + ro0 + cb);
            short8 kf1 = *(const short8*)(Kbuf + ro1 + cb);
            s0 = __builtin_amdgcn_mfma_f32_32x32x16_bf16(kf0, qB[kd], s0, 0, 0, 0);
            s1 = __builtin_amdgcn_mfma_f32_32x32x16_bf16(kf1, qB[kd], s1, 0, 0, 0);
        }
        __builtin_amdgcn_s_setprio(0);

        // ---- P = exp2(S) packed to bf16 A-fragments in-register; l on VALU ----
        u32x4 paw[4];
        PACK_P(s0, s1, paw, l_run);

        // ---- PV: V-frags from swizzled KT LDS ----
        __builtin_amdgcn_s_setprio(1);
        #pragma unroll
        for (int ks = 0; ks < 4; ++ks) {
            union { u32x4 u; short8 s; } pa; pa.u = paw[ks];
            const int cb = (ks * 32 + hi * 16) ^ swz;
            short8 vf0 = *(const short8*)(Ktbuf + ro0 + cb);
            short8 vf1 = *(const short8*)(Ktbuf + ro1 + cb);
            acc0 = __builtin_amdgcn_mfma_f32_32x32x16_bf16(pa.s, vf0, acc0, 0, 0, 0);
            acc1 = __builtin_amdgcn_mfma_f32_32x32x16_bf16(pa.s, vf1, acc1, 0, 0, 0);
        }
        __builtin_amdgcn_s_setprio(0);
    };

    STAGE(0, 0);
    for (int it = 0; it < NS / 128; ++it) {           // 16 sync points
        const int cur = it & 1;
        asm volatile("s_waitcnt vmcnt(0)" ::: "memory");
        __syncthreads();
        if (it < NS / 128 - 1) STAGE(cur ^ 1, (it + 1) * 128);   // flies during compute

        const char* base = (const char*)LDSA + cur * 32768;
        COMPUTE(base);            // kv sub-tile a
        COMPUTE(base + 16384);    // kv sub-tile b (same registers, serial)
    }

    // ---- epilogue: lane q5 holds hi-half of l(q-row q5); merge + redistribute ----
    const float lt = l_run + __shfl_xor(l_run, 32);   // full l for q-row q5
    const float inv = 1.0f / lt;
    #pragma unroll
    for (int r = 0; r < 16; ++r) {
        const int qr = (r & 3) + 8 * (r >> 2) + 4 * hi;
        const float invr = __shfl(inv, qr);           // l(qr) lives at lane qr
        float* orow = outp + ((size_t)b * NS + (qbase + qr)) * NHD + h * ND;
        orow[q5]      = acc0[r] * invr;
        orow[32 + q5] = acc1[r] * invr;
    }
}

extern "C" void kernel_launch(void* const* d_in, const int* in_sizes, int n_in,
                              void* d_out, int out_size, void* d_ws, size_t ws_size,
                              hipStream_t stream) {
    const float* xq = (const float*)d_in[0];
    const float* xk = (const float*)d_in[1];
    const float* Wq = (const float*)d_in[2];
    const float* bq = (const float*)d_in[3];
    const float* Wk = (const float*)d_in[4];
    const float* bk = (const float*)d_in[5];
    float* outp = (float*)d_out;

    // workspace layout (bf16 elements)
    unsigned short* Wqb = (unsigned short*)d_ws;          // 1024x1024
    unsigned short* Wkb = Wqb + 1048576;                  // 1024x1024
    unsigned short* Qb  = Wkb + 1048576;                  // [B][H][S][D]
    unsigned short* Kb  = Qb  + 8388608;                  // [B][H][S][D]
    unsigned short* KTb = Kb  + 8388608;                  // [B][H][D][S]

    // one-time opt-in for 128 KiB dynamic LDS (host-side, graph-capture safe)
    static bool lds_init = false;
    if (!lds_init) {
        hipFuncSetAttribute((const void*)proj_gemm3,
                            hipFuncAttributeMaxDynamicSharedMemorySize, 131072);
        lds_init = true;
    }

    cvt_w_bf16<<<1024, 256, 0, stream>>>(Wq, Wk, Wqb, Wkb);

    const float qscale = 0.125f * 1.4426950408889634f;   // D^-0.5 * log2(e)
    proj_gemm3<<<256, 512, 131072, stream>>>(xq, xk, Wqb, Wkb, bq, bk,
                                             Qb, Kb, KTb, qscale);

    // grid 512 x 512 threads = 2 blocks/CU (16 waves/CU); Bid = x + 8y + 128z linear
    attn_fused<<<dim3(8, 16, 4), 512, 0, stream>>>(Qb, Kb, KTb, outp);
}